// Round 13
// baseline (76.563 us; speedup 1.0000x reference)
//
#include <hip/hip_runtime.h>
#include <hip/hip_bf16.h>

#define HIDDEN 1024
#define HEADS  2560

// GEMM geometry: 256x128 tile, BK=32, grid = (8192/256)*(2560/128) = 640.
// 8 waves (4M x 2N), per-wave 64x64 = acc[4][4]. Pair-packed LDS (logical row
// r -> physical row r>>1, half (r&1)*64) -> 128B physical rows, R12-verified
// zero-conflict swizzle. Ring-3 buffers: 3 * 24576 = 73728 B -> 2 blocks/CU.
// Uniform 3 gload_lds/thread/tile -> counted vmcnt(3) at tile boundaries
// (T4: never drain to 0 in the main loop).
#define BM 256
#define BN 128
#define BK 32
#define NT (HIDDEN / BK)        // 32 K-tiles
#define ABYT (BM * BK * 2)      // 16384
#define BBYT (BN * BK * 2)      // 8192
#define BUFSZ (ABYT + BBYT)     // 24576

typedef float  f32x4  __attribute__((ext_vector_type(4)));
typedef __bf16 bf16x8 __attribute__((ext_vector_type(8)));
typedef __bf16 bf16x4 __attribute__((ext_vector_type(4)));

__device__ __forceinline__ void gload_lds16(const void* g, void* l) {
    __builtin_amdgcn_global_load_lds(
        (const __attribute__((address_space(1))) unsigned int*)g,
        (__attribute__((address_space(3))) unsigned int*)l, 16, 0, 0);
}

// ---------------------------------------------------------------------------
// Fused pass 1: blocks [0,640) transpose W f32[K][N] -> Wt bf16[N][K];
//               blocks [640,...) convert x f32 -> bf16.
// ---------------------------------------------------------------------------
__global__ __launch_bounds__(256)
void cvt_all(const float* __restrict__ x, const float* __restrict__ W,
             __bf16* __restrict__ xc, __bf16* __restrict__ Wt, int n8)
{
    if (blockIdx.x < 640) {
        __shared__ __bf16 tile[64][72];
        const int t  = threadIdx.x;
        const int n0 = (blockIdx.x % 40) * 64;
        const int k0 = (blockIdx.x / 40) * 64;

        #pragma unroll
        for (int i = 0; i < 4; ++i) {
            const int k    = (t >> 4) + i * 16;
            const int col4 = (t & 15) * 4;
            const float4 v = *reinterpret_cast<const float4*>(
                W + (size_t)(k0 + k) * HEADS + n0 + col4);
            bf16x4 h;
            h[0] = (__bf16)v.x; h[1] = (__bf16)v.y; h[2] = (__bf16)v.z; h[3] = (__bf16)v.w;
            *reinterpret_cast<bf16x4*>(&tile[k][col4]) = h;
        }
        __syncthreads();
        #pragma unroll
        for (int i = 0; i < 4; ++i) {
            const int n  = (t >> 4) + i * 16;
            const int k4 = (t & 15) * 4;
            bf16x4 h;
            h[0] = tile[k4 + 0][n]; h[1] = tile[k4 + 1][n];
            h[2] = tile[k4 + 2][n]; h[3] = tile[k4 + 3][n];
            *reinterpret_cast<bf16x4*>(Wt + (size_t)(n0 + n) * HIDDEN + k0 + k4) = h;
        }
    } else {
        int idx    = (blockIdx.x - 640) * blockDim.x + threadIdx.x;
        int stride = (gridDim.x - 640) * blockDim.x;
        for (int i = idx; i < n8; i += stride) {
            const float4 a = *reinterpret_cast<const float4*>(x + (size_t)i * 8);
            const float4 b = *reinterpret_cast<const float4*>(x + (size_t)i * 8 + 4);
            bf16x8 h;
            h[0] = (__bf16)a.x; h[1] = (__bf16)a.y; h[2] = (__bf16)a.z; h[3] = (__bf16)a.w;
            h[4] = (__bf16)b.x; h[5] = (__bf16)b.y; h[6] = (__bf16)b.z; h[7] = (__bf16)b.w;
            *reinterpret_cast<bf16x8*>(xc + (size_t)i * 8) = h;
        }
    }
}

// ---------------------------------------------------------------------------
// Pass 2: ring-3 counted-vmcnt pipeline. Per K-tile k: {issue 3 gload_lds for
// tile k+2 into buf (k+2)%3 | 8 ds_read_b128 + 16 MFMA from buf k%3 |
// vmcnt(3) (tile k+1 landed; k+2 still in flight) | one s_barrier}.
// Race-freedom: buf (k+2)%3's last readers ran at tile k-1 and drained
// before that tile's end barrier; its last writes completed at tile k-2's
// boundary wait.
// ---------------------------------------------------------------------------
__global__ __launch_bounds__(512, 4)
void gemm_r3(const __bf16* __restrict__ A, const __bf16* __restrict__ Bt,
             const float* __restrict__ bias, float* __restrict__ out)
{
    __shared__ char lds[3 * BUFSZ];   // 73728 B

    const int t    = threadIdx.x;
    const int lane = t & 63;
    const int w    = t >> 6;      // 0..7
    const int wr   = w & 3;       // 0..3 : 64-row slab
    const int wc   = w >> 2;      // 0..1 : 64-col slab
    const int lhi  = lane >> 4;   // 0..3
    const int llo  = lane & 15;   // 0..15

    // XCD-grouped bijective remap (640 = 8 * 80): XCD x -> bx in [4x,4x+4)
    // (4 A-slabs = 2MB, L2-resident); B panels (5MB) stream via L3.
    const int g   = (blockIdx.x & 7) * 80 + (blockIdx.x >> 3);
    const int bx  = g / 20;
    const int by  = g % 20;
    const int bm0 = bx * BM;
    const int bn0 = by * BN;

    // ---- staging descriptors (pair-packed). LDS physical byte d: prow=d>>7,
    // il = (d&127) ^ ((prow&7)<<4); logical row lr = (prow<<1)|(il>>6),
    // k-byte c = il&63. Sweep d+8192: prow+=64 (prow&7 inv) -> lr+=128 ->
    // uniform src advance 128*2048 = 262144 B.
    const unsigned dA = (unsigned)(t * 16);
    {
    }
    const unsigned prowA = dA >> 7;
    const unsigned ilA   = (dA & 127u) ^ ((prowA & 7u) << 4);
    const char* asrc0 = (const char*)A
        + (size_t)(bm0 + (int)((prowA << 1) | (ilA >> 6))) * 2048 + (ilA & 63u);
    const char* bsrc0 = (const char*)Bt
        + (size_t)(bn0 + (int)((prowA << 1) | (ilA >> 6))) * 2048 + (ilA & 63u);
    // dests: buf base + dA (A region) / buf base + ABYT + dA (B region)

    // ---- fragment read offsets (R12-verified zero-conflict pattern).
    // prow&7 = (llo>>1)&7; klo < 128; row bases multiples of 128 -> no carry.
    const unsigned klo = (unsigned)(((llo & 1) << 6) | (lhi << 4))
                       ^ (unsigned)(((llo >> 1) & 7) << 4);
    const unsigned laneR = (unsigned)((llo >> 1) * 128);
    const unsigned baseA = (unsigned)(wr * 4096) + laneR;                  // + m*1024
    const unsigned baseB = (unsigned)ABYT + (unsigned)(wc * 4096) + laneR; // + n*1024

    f32x4 acc[4][4];
    #pragma unroll
    for (int m = 0; m < 4; ++m)
        #pragma unroll
        for (int n = 0; n < 4; ++n)
            acc[m][n] = f32x4{0.f, 0.f, 0.f, 0.f};

    char* const lb = (char*)lds;

    // ---- prologue: stage T0 -> buf0, T1 -> buf1 (6 loads); T0 done; barrier
    gload_lds16(asrc0,               lb + dA);
    gload_lds16(asrc0 + 262144,      lb + dA + 8192);
    gload_lds16(bsrc0,               lb + ABYT + dA);
    gload_lds16(asrc0 + 64,          lb + BUFSZ + dA);
    gload_lds16(asrc0 + 64 + 262144, lb + BUFSZ + dA + 8192);
    gload_lds16(bsrc0 + 64,          lb + BUFSZ + ABYT + dA);
    asm volatile("s_waitcnt vmcnt(3)" ::: "memory");
    __builtin_amdgcn_s_barrier();

    int bi = 0;   // k % 3
    int si = 2;   // (k+2) % 3
    for (int k = 0; k < NT; ++k) {
        const char* buf = lb + bi * BUFSZ;

        // ---- issue: stage tile k+2 (2 tile-times of latency cover)
        if (k + 2 < NT) {
            char* nbf = lb + si * BUFSZ;
            const int koff = (k + 2) * 64;
            gload_lds16(asrc0 + koff,          nbf + dA);
            gload_lds16(asrc0 + koff + 262144, nbf + dA + 8192);
            gload_lds16(bsrc0 + koff,          nbf + ABYT + dA);
        }

        // ---- compute: 8 ds_read_b128 + 16 MFMA, compiler-scheduled
        bf16x8 af[4], bfr[4];
        #pragma unroll
        for (int m = 0; m < 4; ++m)
            af[m]  = *(const bf16x8*)(buf + baseA + m * 1024 + klo);
        #pragma unroll
        for (int n = 0; n < 4; ++n)
            bfr[n] = *(const bf16x8*)(buf + baseB + n * 1024 + klo);
        #pragma unroll
        for (int m = 0; m < 4; ++m)
            #pragma unroll
            for (int n = 0; n < 4; ++n)
                acc[m][n] = __builtin_amdgcn_mfma_f32_16x16x32_bf16(
                    af[m], bfr[n], acc[m][n], 0, 0, 0);

        // ---- boundary: tile k+1's loads must have landed; k+2's stay in flight
        if (k < NT - 2) asm volatile("s_waitcnt vmcnt(3)" ::: "memory");
        else            asm volatile("s_waitcnt vmcnt(0)" ::: "memory");
        __builtin_amdgcn_s_barrier();

        bi = (bi == 2) ? 0 : bi + 1;
        si = (si == 2) ? 0 : si + 1;
    }

    // ---- epilogue: bias + sigmoid; C/D: col = lane&15, row = (lane>>4)*4+reg
    #pragma unroll
    for (int n = 0; n < 4; ++n) {
        const int col  = bn0 + wc * 64 + n * 16 + llo;
        const float bv = bias[col];
        #pragma unroll
        for (int m = 0; m < 4; ++m) {
            const int row0 = bm0 + wr * 64 + m * 16 + lhi * 4;
            #pragma unroll
            for (int r = 0; r < 4; ++r) {
                const float z = acc[m][n][r] + bv;
                out[(size_t)(row0 + r) * HEADS + col] = __fdividef(1.0f, 1.0f + __expf(-z));
            }
        }
    }
}

// ---------------------------------------------------------------------------
// Fallback (R1 fused kernel) if workspace is too small.
// ---------------------------------------------------------------------------
#define FBM 128
#define FBN 128
#define FBK 32
#define FLDK 40

__global__ __launch_bounds__(256)
void lch_gemm(const float* __restrict__ x, const float* __restrict__ W,
              const float* __restrict__ b, float* __restrict__ out)
{
    __shared__ __bf16 As[FBM][FLDK];
    __shared__ __bf16 Bs[FBN][FLDK];

    const int t   = threadIdx.x;
    const int bm0 = blockIdx.x * FBM;
    const int bn0 = blockIdx.y * FBN;
    const int lane = t & 63;
    const int wid  = t >> 6;
    const int wr   = wid >> 1;
    const int wc   = wid & 1;
    const int lhi  = lane >> 4;
    const int llo  = lane & 15;

    f32x4 acc[4][4];
    #pragma unroll
    for (int i = 0; i < 4; ++i)
        #pragma unroll
        for (int j = 0; j < 4; ++j)
            acc[i][j] = f32x4{0.f, 0.f, 0.f, 0.f};

    const int bn_col  = t & 127;
    const int bk_base = (t >> 7) * 16;

    for (int k0 = 0; k0 < HIDDEN; k0 += FBK) {
        #pragma unroll
        for (int i = 0; i < 4; ++i) {
            const int f   = t + i * 256;
            const int row = f >> 3;
            const int c4  = (f & 7) * 4;
            const float4 v = *reinterpret_cast<const float4*>(
                x + (size_t)(bm0 + row) * HIDDEN + k0 + c4);
            bf16x4 h;
            h[0] = (__bf16)v.x; h[1] = (__bf16)v.y;
            h[2] = (__bf16)v.z; h[3] = (__bf16)v.w;
            *reinterpret_cast<bf16x4*>(&As[row][c4]) = h;
        }
        {
            const float* wp = W + (size_t)(k0 + bk_base) * HEADS + bn0 + bn_col;
            bf16x8 h0, h1;
            #pragma unroll
            for (int i = 0; i < 8; ++i) h0[i] = (__bf16)wp[(size_t)i * HEADS];
            #pragma unroll
            for (int i = 0; i < 8; ++i) h1[i] = (__bf16)wp[(size_t)(i + 8) * HEADS];
            *reinterpret_cast<bf16x8*>(&Bs[bn_col][bk_base])     = h0;
            *reinterpret_cast<bf16x8*>(&Bs[bn_col][bk_base + 8]) = h1;
        }
        __syncthreads();

        bf16x8 af[4], bfr[4];
        #pragma unroll
        for (int i = 0; i < 4; ++i)
            af[i] = *reinterpret_cast<const bf16x8*>(&As[wr * 64 + i * 16 + llo][lhi * 8]);
        #pragma unroll
        for (int j = 0; j < 4; ++j)
            bfr[j] = *reinterpret_cast<const bf16x8*>(&Bs[wc * 64 + j * 16 + llo][lhi * 8]);
        #pragma unroll
        for (int i = 0; i < 4; ++i)
            #pragma unroll
            for (int j = 0; j < 4; ++j)
                acc[i][j] = __builtin_amdgcn_mfma_f32_16x16x32_bf16(
                    af[i], bfr[j], acc[i][j], 0, 0, 0);
        __syncthreads();
    }

    #pragma unroll
    for (int j = 0; j < 4; ++j) {
        const int col  = bn0 + wc * 64 + j * 16 + llo;
        const float bv = b[col];
        #pragma unroll
        for (int i = 0; i < 4; ++i) {
            const int row0 = bm0 + wr * 64 + i * 16 + lhi * 4;
            #pragma unroll
            for (int r = 0; r < 4; ++r) {
                const float z = acc[i][j][r] + bv;
                out[(size_t)(row0 + r) * HEADS + col] = 1.0f / (1.0f + __expf(-z));
            }
        }
    }
}

extern "C" void kernel_launch(void* const* d_in, const int* in_sizes, int n_in,
                              void* d_out, int out_size, void* d_ws, size_t ws_size,
                              hipStream_t stream) {
    const float* x = (const float*)d_in[0];
    const float* W = (const float*)d_in[1];
    const float* b = (const float*)d_in[2];
    float* out     = (float*)d_out;

    const int M = in_sizes[0] / HIDDEN;   // 8192

    const size_t xc_bytes = (size_t)M * HIDDEN * sizeof(__bf16);
    const size_t wt_bytes = (size_t)HEADS * HIDDEN * sizeof(__bf16);

    if (ws_size >= xc_bytes + wt_bytes && (M % BM) == 0) {
        __bf16* xc = (__bf16*)d_ws;
        __bf16* Wt = (__bf16*)((char*)d_ws + xc_bytes);

        cvt_all<<<640 + 2048, 256, 0, stream>>>(x, W, xc, Wt, M * HIDDEN / 8);

        const int nwg = (M / BM) * (HEADS / BN);   // 32 * 20 = 640
        gemm_r3<<<nwg, 512, 0, stream>>>(xc, Wt, b, out);
    } else {
        dim3 grid(M / FBM, HEADS / FBN);
        lch_gemm<<<grid, dim3(256), 0, stream>>>(x, W, b, out);
    }
}